// Round 10
// baseline (382.249 us; speedup 1.0000x reference)
//
#include <hip/hip_runtime.h>
#include <hip/hip_cooperative_groups.h>
#include <math.h>

namespace cg = cooperative_groups;

#define N_ 2048
#define C_ 1000
#define D_ 768
#define K_ 5
#define CAP_ 128
#define MAXS_ 100
#define LB_ 128   // k_lame blocks
#define LT_ 512   // k_lame threads (8 waves x 2 rows = 16 rows/block)

typedef unsigned short ushort_t;
typedef unsigned int uint_t;

__device__ inline float bflo(uint_t v) { union { uint_t i; float f; } c; c.i = v << 16; return c.f; }
__device__ inline float bfhi(uint_t v) { union { uint_t i; float f; } c; c.i = v & 0xffff0000u; return c.f; }
__device__ inline ushort_t f2b(float f) {   // RNE, finite inputs only
    union { float f; uint_t i; } c; c.f = f;
    return (ushort_t)((c.i + 0x7fffu + ((c.i >> 16) & 1u)) >> 16);
}
__device__ inline uint_t pk(float a, float b) { return (uint_t)f2b(a) | ((uint_t)f2b(b) << 16); }

// ---------------- K1: row-normalize feats ----------------
__global__ __launch_bounds__(256) void k_norm(const float* __restrict__ feats,
                                              float* __restrict__ fn) {
    const int r = blockIdx.x, tid = threadIdx.x;
    __shared__ float red[256];
    const float* row = feats + (size_t)r * D_;
    float ss = 0.f;
    for (int c = tid; c < D_; c += 256) { float v = row[c]; ss += v * v; }
    red[tid] = ss; __syncthreads();
    for (int s = 128; s > 0; s >>= 1) { if (tid < s) red[tid] += red[tid + s]; __syncthreads(); }
    const float n = sqrtf(red[0]); __syncthreads();
    for (int c = tid; c < D_; c += 256) fn[(size_t)r * D_ + c] = row[c] / n;
}

// ---------------- K2: sim = fn * fn^T  (f32, 128x128 tile, 512 thr, 8x4 per thread) ----------------
#define GTM 128
#define GTN 128
#define GBK 32
__global__ __launch_bounds__(512, 2) void k_gemm(const float* __restrict__ A,
                                                 float* __restrict__ Csim) {
    __shared__ float As[GBK][GTM + 4];
    __shared__ float Bs[GBK][GTN + 4];
    const int tid = threadIdx.x;
    const int tx = tid & 31;          // 32 col-groups of 4
    const int ty = tid >> 5;          // 16 row-groups of 8
    const int m0 = blockIdx.y * GTM, n0 = blockIdx.x * GTN;
    float acc[8][4] = {};
    for (int k0 = 0; k0 < D_; k0 += GBK) {
        #pragma unroll
        for (int l = 0; l < 2; l++) {            // A tile: 128x32 = 1024 float4
            int idx = tid + l * 512;
            int mm = idx >> 3, kk = (idx & 7) * 4;
            float4 v = *(const float4*)(A + (size_t)(m0 + mm) * D_ + k0 + kk);
            As[kk][mm] = v.x; As[kk + 1][mm] = v.y; As[kk + 2][mm] = v.z; As[kk + 3][mm] = v.w;
        }
        #pragma unroll
        for (int l = 0; l < 2; l++) {            // B tile: 128x32
            int idx = tid + l * 512;
            int mm = idx >> 3, kk = (idx & 7) * 4;
            float4 v = *(const float4*)(A + (size_t)(n0 + mm) * D_ + k0 + kk);
            Bs[kk][mm] = v.x; Bs[kk + 1][mm] = v.y; Bs[kk + 2][mm] = v.z; Bs[kk + 3][mm] = v.w;
        }
        __syncthreads();
        #pragma unroll
        for (int kk = 0; kk < GBK; kk++) {
            float4 a0 = *(const float4*)&As[kk][ty * 8];
            float4 a1 = *(const float4*)&As[kk][ty * 8 + 4];
            float4 bv = *(const float4*)&Bs[kk][tx * 4];
            float a[8] = { a0.x, a0.y, a0.z, a0.w, a1.x, a1.y, a1.z, a1.w };
            float b[4] = { bv.x, bv.y, bv.z, bv.w };
            #pragma unroll
            for (int i = 0; i < 8; i++)
                #pragma unroll
                for (int j = 0; j < 4; j++) acc[i][j] += a[i] * b[j];
        }
        __syncthreads();
    }
    #pragma unroll
    for (int i = 0; i < 8; i++) {
        float4 st = make_float4(acc[i][0], acc[i][1], acc[i][2], acc[i][3]);
        *(float4*)(Csim + (size_t)(m0 + ty * 8 + i) * N_ + n0 + tx * 4) = st;
    }
}

// ---------------- K3: wave-per-row top-6 by (dist asc, idx asc); drop self; scatter ----------------
// Selection over the strict total order (d, j) is scan-order-independent -> identical knn
// to the tree-merge version. No __syncthreads, no LDS.
__global__ __launch_bounds__(256) void k_topk(const float* __restrict__ sim,
                                              int* __restrict__ knn,
                                              int* __restrict__ indeg,
                                              int* __restrict__ inlist) {
    const int wave = threadIdx.x >> 6, lane = threadIdx.x & 63;
    const int r = blockIdx.x * 4 + wave;
    float bd[6]; int bi[6];
    #pragma unroll
    for (int k = 0; k < 6; k++) { bd[k] = INFINITY; bi[k] = 0x7fffffff; }
    const float* srow = sim + (size_t)r * N_;
    for (int j = lane; j < N_; j += 64) {
        const float s = srow[j];
        const float d = sqrtf(fmaxf(2.f - 2.f * s, 0.f));
        if (d < bd[5] || (d == bd[5] && j < bi[5])) {
            int k = 5;
            while (k > 0 && (d < bd[k - 1] || (d == bd[k - 1] && j < bi[k - 1]))) {
                bd[k] = bd[k - 1]; bi[k] = bi[k - 1]; k--;
            }
            bd[k] = d; bi[k] = j;
        }
    }
    #pragma unroll
    for (int o = 1; o <= 32; o <<= 1) {   // 6-step butterfly across 64 lanes
        float od[6]; int oj[6];
        #pragma unroll
        for (int k = 0; k < 6; k++) { od[k] = __shfl_xor(bd[k], o); oj[k] = __shfl_xor(bi[k], o); }
        float md[6]; int mi[6];
        int p = 0, q = 0;
        #pragma unroll
        for (int k = 0; k < 6; k++) {
            const bool take1 = (bd[p] < od[q]) || (bd[p] == od[q] && bi[p] < oj[q]);
            if (take1) { md[k] = bd[p]; mi[k] = bi[p]; p++; }
            else       { md[k] = od[q]; mi[k] = oj[q]; q++; }
        }
        #pragma unroll
        for (int k = 0; k < 6; k++) { bd[k] = md[k]; bi[k] = mi[k]; }
    }
    if (lane < K_) {
        const int j = bi[1 + lane];        // drop rank-0 (self)
        knn[(size_t)r * K_ + lane] = j;
        const int pos = atomicAdd(&indeg[j], 1);
        if (pos < CAP_) inlist[(size_t)j * CAP_ + pos] = r;
    }
}

// ---------------- K5: cooperative LAME — sort/unary prologue + iterate (flag-prefetch) ----------------
__global__ __launch_bounds__(LT_) void k_lame(
    const float* __restrict__ logits, const int* __restrict__ knn,
    const int* __restrict__ indeg, const int* __restrict__ inlist,
    ushort_t* __restrict__ YA, ushort_t* __restrict__ YB,
    float* __restrict__ partials, int* __restrict__ flag,
    float* __restrict__ out)
{
    cg::grid_group grid = cg::this_grid();
    const int tid = threadIdx.x;
    const int wave = tid >> 6, lane = tid & 63;
    const int rbase = blockIdx.x * 16 + wave * 2;   // rows rbase, rbase+1
    const int c0 = lane * 16;
    const bool msk0 = lane <= 62;   // cols c0..c0+7 valid
    const bool msk1 = lane <= 61;   // cols c0+8..c0+15 valid

    // ---- prologue B: stage neighbor lists in LDS, sort in-lists (deterministic) ----
    __shared__ int nb[16][K_ + CAP_ + 3];
    __shared__ int cnts[16];
    #pragma unroll
    for (int rr = 0; rr < 2; rr++) {
        const int w = wave * 2 + rr, r = rbase + rr;
        if (lane == 0) cnts[w] = K_ + min(indeg[r], CAP_);
        if (lane < K_) nb[w][lane] = knn[r * K_ + lane];
        for (int t = lane; t < CAP_; t += 64) nb[w][K_ + t] = inlist[(size_t)r * CAP_ + t];
    }
    __syncthreads();
    if (lane < 2) {   // insertion-sort each row's in-list ascending
        const int w = wave * 2 + lane;
        int* L = &nb[w][K_];
        const int cn = cnts[w] - K_;
        for (int a = 1; a < cn; a++) {
            const int key = L[a];
            int b = a - 1;
            while (b >= 0 && L[b] > key) { L[b + 1] = L[b]; b--; }
            L[b + 1] = key;
        }
    }
    __syncthreads();
    const int cnt2[2] = { cnts[wave * 2], cnts[wave * 2 + 1] };

    // ---- prologue C: u = -log(softmax(logits)+1e-10) in registers ----
    float u[2][16];
    #pragma unroll
    for (int rr = 0; rr < 2; rr++) {
        const float* lp = logits + (size_t)(rbase + rr) * C_;
        float l[16];
        #pragma unroll
        for (int q = 0; q < 4; q++) {
            const int off = c0 + q * 4;
            const int ao = (off + 3 < C_) ? off : 0;   // clamp: input buffer exactly sized
            float4 v = *(const float4*)(lp + ao);
            l[q * 4 + 0] = v.x; l[q * 4 + 1] = v.y; l[q * 4 + 2] = v.z; l[q * 4 + 3] = v.w;
        }
        float mm = -INFINITY;
        #pragma unroll
        for (int k = 0; k < 8; k++) mm = fmaxf(mm, msk0 ? l[k] : -INFINITY);
        #pragma unroll
        for (int k = 8; k < 16; k++) mm = fmaxf(mm, msk1 ? l[k] : -INFINITY);
        #pragma unroll
        for (int o = 32; o > 0; o >>= 1) mm = fmaxf(mm, __shfl_xor(mm, o));
        float e[16];
        float s = 0.f;
        #pragma unroll
        for (int k = 0; k < 8; k++) { e[k] = msk0 ? expf(l[k] - mm) : 0.f; s += e[k]; }
        #pragma unroll
        for (int k = 8; k < 16; k++) { e[k] = msk1 ? expf(l[k] - mm) : 0.f; s += e[k]; }
        #pragma unroll
        for (int o = 32; o > 0; o >>= 1) s += __shfl_xor(s, o);
        const float inv = 1.f / s;
        #pragma unroll
        for (int k = 0; k < 16; k++) u[rr][k] = -logf(e[k] * inv + 1e-10f);
    }

    // gather neighbor-sum of src into acc[16] for row-pair member rr
    auto gather = [&](const ushort_t* __restrict__ src, int rr, float* acc) {
        const int w = wave * 2 + rr, cn = cnt2[rr];
        auto acc16 = [&](uint4 p, uint4 q) {
            acc[0] += bflo(p.x); acc[1] += bfhi(p.x); acc[2] += bflo(p.y); acc[3] += bfhi(p.y);
            acc[4] += bflo(p.z); acc[5] += bfhi(p.z); acc[6] += bflo(p.w); acc[7] += bfhi(p.w);
            acc[8] += bflo(q.x); acc[9] += bfhi(q.x); acc[10] += bflo(q.y); acc[11] += bfhi(q.y);
            acc[12] += bflo(q.z); acc[13] += bfhi(q.z); acc[14] += bflo(q.w); acc[15] += bfhi(q.w);
        };
        int t = 0;
        for (; t + 2 <= cn; t += 2) {
            const int n0 = nb[w][t], n1 = nb[w][t + 1];
            const uint4 p0 = *(const uint4*)(src + (size_t)n0 * C_ + c0);
            const uint4 p1 = *(const uint4*)(src + (size_t)n0 * C_ + c0 + 8);
            const uint4 q0 = *(const uint4*)(src + (size_t)n1 * C_ + c0);
            const uint4 q1 = *(const uint4*)(src + (size_t)n1 * C_ + c0 + 8);
            acc16(p0, p1); acc16(q0, q1);
        }
        if (t < cn) {
            const int n0 = nb[w][t];
            const uint4 p0 = *(const uint4*)(src + (size_t)n0 * C_ + c0);
            const uint4 p1 = *(const uint4*)(src + (size_t)n0 * C_ + c0 + 8);
            acc16(p0, p1);
        }
    };

    // softmax(0.5*acc - u[rr]) -> dst row; returns row energy -(m+logS)
    auto smax = [&](int rr, const float* acc, ushort_t* __restrict__ dst) -> float {
        const int r = rbase + rr;
        float z[16];
        #pragma unroll
        for (int k = 0; k < 16; k++) z[k] = 0.5f * acc[k] - u[rr][k];
        float mm = -INFINITY;
        #pragma unroll
        for (int k = 0; k < 8; k++) mm = fmaxf(mm, msk0 ? z[k] : -INFINITY);
        #pragma unroll
        for (int k = 8; k < 16; k++) mm = fmaxf(mm, msk1 ? z[k] : -INFINITY);
        #pragma unroll
        for (int o = 32; o > 0; o >>= 1) mm = fmaxf(mm, __shfl_xor(mm, o));
        float e[16];
        float s = 0.f;
        #pragma unroll
        for (int k = 0; k < 8; k++) { e[k] = msk0 ? expf(z[k] - mm) : 0.f; s += e[k]; }
        #pragma unroll
        for (int k = 8; k < 16; k++) { e[k] = msk1 ? expf(z[k] - mm) : 0.f; s += e[k]; }
        #pragma unroll
        for (int o = 32; o > 0; o >>= 1) s += __shfl_xor(s, o);
        const float inv = 1.f / s;
        if (msk0) {
            uint4 w;
            w.x = pk(e[0] * inv, e[1] * inv); w.y = pk(e[2] * inv, e[3] * inv);
            w.z = pk(e[4] * inv, e[5] * inv); w.w = pk(e[6] * inv, e[7] * inv);
            *(uint4*)(dst + (size_t)r * C_ + c0) = w;
        }
        if (msk1) {
            uint4 w;
            w.x = pk(e[8] * inv, e[9] * inv); w.y = pk(e[10] * inv, e[11] * inv);
            w.z = pk(e[12] * inv, e[13] * inv); w.w = pk(e[14] * inv, e[15] * inv);
            *(uint4*)(dst + (size_t)r * C_ + c0 + 8) = w;
        }
        return -(mm + logf(s));   // == sum_c Y*(logY - z), exact closed form
    };

    // ---- Y0 = softmax(-unary) -> YA ----
    {
        float zacc[16];
        #pragma unroll
        for (int k = 0; k < 16; k++) zacc[k] = 0.f;
        smax(0, zacc, YA);
        smax(1, zacc, YA);
    }
    if (blockIdx.x == 0 && tid == 0) { flag[0] = 0; flag[1] = 0; }
    grid.sync();

    // Main loop with flag-prefetch: the lagged done-flag is LOADED right after grid.sync
    // (slot (it+1)&1, last written at it-1, i.e. before the sync we just passed -> race-free)
    // and CONSUMED at the top of iteration it+1 after the gather issues -> its L2-miss
    // latency hides under the gather. Stop iteration & fin are identical to round-9
    // (done(itd) -> break with fin = dst(itd+1)); one gather is wasted at exit.
    float oldE = INFINITY;
    int flagpref = 0;
    const ushort_t* fin = YB;
    for (int it = 0; it < MAXS_; ++it) {
        const ushort_t* src = (it & 1) ? YB : YA;
        ushort_t* dst = (it & 1) ? YA : YB;
        float acc0[16], acc1[16];
        #pragma unroll
        for (int k = 0; k < 16; k++) { acc0[k] = 0.f; acc1[k] = 0.f; }
        gather(src, 0, acc0);
        gather(src, 1, acc1);
        if (flagpref) break;   // uniform: same slot/value in every block; fin = prev dst
        const float E0 = smax(0, acc0, dst);
        const float E1 = smax(1, acc1, dst);
        if (lane == 0) {
            partials[(size_t)(it & 1) * N_ + rbase] = E0;
            partials[(size_t)(it & 1) * N_ + rbase + 1] = E1;
        }
        grid.sync();
        if (blockIdx.x == 0 && wave == 0) {
            const float* P = partials + (size_t)(it & 1) * N_;
            float e = 0.f;
            #pragma unroll
            for (int q = 0; q < 32; q += 4) {
                float4 v = *(const float4*)(P + lane * 32 + q);
                e += ((v.x + v.y) + v.z) + v.w;
            }
            #pragma unroll
            for (int o = 32; o > 0; o >>= 1) e += __shfl_xor(e, o);
            const bool done = (it > 1) && (fabsf(e - oldE) <= 1e-8f * fabsf(oldE));
            oldE = e;
            if (lane == 0) flag[it & 1] = done ? 1 : 0;
        }
        flagpref = ((volatile const int*)flag)[(it + 1) & 1];  // issue now, consume next iter
        fin = dst;
    }

    #pragma unroll
    for (int rr = 0; rr < 2; rr++) {
        const int r = rbase + rr;
        #pragma unroll
        for (int q = 0; q < 4; q++) {
            if (c0 + q * 4 + 3 < C_) {
                const uint2 w = *(const uint2*)(fin + (size_t)r * C_ + c0 + q * 4);
                float4 o;
                o.x = bflo(w.x); o.y = bfhi(w.x); o.z = bflo(w.y); o.w = bfhi(w.y);
                *(float4*)(out + (size_t)r * C_ + c0 + q * 4) = o;
            }
        }
    }
}

extern "C" void kernel_launch(void* const* d_in, const int* in_sizes, int n_in,
                              void* d_out, int out_size, void* d_ws, size_t ws_size,
                              hipStream_t stream) {
    const float* logits = (const float*)d_in[0];
    const float* feats  = (const float*)d_in[1];
    float* out = (float*)d_out;
    char* ws = (char*)d_ws;

    size_t off = 0;
    auto alloc = [&](size_t b) { size_t o = off; off += (b + 255) & ~(size_t)255; return o; };
    float* fn      = (float*)(ws + alloc((size_t)N_ * D_ * 4));
    float* sim     = (float*)(ws + alloc((size_t)N_ * N_ * 4));   // reused as YA/YB after topk
    int*   knn     = (int*)(ws + alloc((size_t)N_ * K_ * 4));
    int*   indeg   = (int*)(ws + alloc((size_t)N_ * 4));
    int*   inlist  = (int*)(ws + alloc((size_t)N_ * CAP_ * 4));
    float* partials= (float*)(ws + alloc((size_t)2 * N_ * 4));
    int*   flag    = (int*)(ws + alloc(256));
    if (off > ws_size) return;

    ushort_t* YA = (ushort_t*)sim;             // 2 * N*C*2 B = 8.2 MB <= N*N*4 B
    ushort_t* YB = YA + (size_t)N_ * C_;

    k_norm <<<N_, 256, 0, stream>>>(feats, fn);
    (void)hipMemsetAsync(indeg, 0, (size_t)N_ * 4, stream);
    k_gemm <<<dim3(N_ / GTN, N_ / GTM), 512, 0, stream>>>(fn, sim);
    k_topk <<<N_ / 4, 256, 0, stream>>>(sim, knn, indeg, inlist);

    const float* p_logits = logits;
    const int* p_knn = knn;
    const int* p_indeg = indeg;
    const int* p_inlist = inlist;
    ushort_t* p_YA = YA;
    ushort_t* p_YB = YB;
    float* p_part = partials;
    int* p_flag = flag;
    float* p_out = out;
    void* args[] = { &p_logits, &p_knn, &p_indeg, &p_inlist, &p_YA, &p_YB, &p_part, &p_flag, &p_out };
    (void)hipLaunchCooperativeKernel((void*)k_lame, dim3(LB_), dim3(LT_), args, 0, stream);
}

// Round 11
// 357.604 us; speedup vs baseline: 1.0689x; 1.0689x over previous
//
#include <hip/hip_runtime.h>
#include <hip/hip_cooperative_groups.h>
#include <math.h>

namespace cg = cooperative_groups;

#define N_ 2048
#define C_ 1000
#define D_ 768
#define K_ 5
#define CAP_ 128
#define MAXS_ 100
#define LB_ 128   // k_lame blocks
#define LT_ 512   // k_lame threads (8 waves x 2 rows = 16 rows/block)

typedef unsigned short ushort_t;
typedef unsigned int uint_t;

__device__ inline float bflo(uint_t v) { union { uint_t i; float f; } c; c.i = v << 16; return c.f; }
__device__ inline float bfhi(uint_t v) { union { uint_t i; float f; } c; c.i = v & 0xffff0000u; return c.f; }
__device__ inline ushort_t f2b(float f) {   // RNE, finite inputs only
    union { float f; uint_t i; } c; c.f = f;
    return (ushort_t)((c.i + 0x7fffu + ((c.i >> 16) & 1u)) >> 16);
}
__device__ inline uint_t pk(float a, float b) { return (uint_t)f2b(a) | ((uint_t)f2b(b) << 16); }

// ---------------- K1: row-normalize feats ----------------
__global__ __launch_bounds__(256) void k_norm(const float* __restrict__ feats,
                                              float* __restrict__ fn) {
    const int r = blockIdx.x, tid = threadIdx.x;
    __shared__ float red[256];
    const float* row = feats + (size_t)r * D_;
    float ss = 0.f;
    for (int c = tid; c < D_; c += 256) { float v = row[c]; ss += v * v; }
    red[tid] = ss; __syncthreads();
    for (int s = 128; s > 0; s >>= 1) { if (tid < s) red[tid] += red[tid + s]; __syncthreads(); }
    const float n = sqrtf(red[0]); __syncthreads();
    for (int c = tid; c < D_; c += 256) fn[(size_t)r * D_ + c] = row[c] / n;
}

// ---------------- K2: sim = fn * fn^T  (f32, 128x128 tile, 512 thr, 8x4 per thread) ----------------
#define GTM 128
#define GTN 128
#define GBK 32
__global__ __launch_bounds__(512, 2) void k_gemm(const float* __restrict__ A,
                                                 float* __restrict__ Csim) {
    __shared__ float As[GBK][GTM + 4];
    __shared__ float Bs[GBK][GTN + 4];
    const int tid = threadIdx.x;
    const int tx = tid & 31;          // 32 col-groups of 4
    const int ty = tid >> 5;          // 16 row-groups of 8
    const int m0 = blockIdx.y * GTM, n0 = blockIdx.x * GTN;
    float acc[8][4] = {};
    for (int k0 = 0; k0 < D_; k0 += GBK) {
        #pragma unroll
        for (int l = 0; l < 2; l++) {            // A tile: 128x32 = 1024 float4
            int idx = tid + l * 512;
            int mm = idx >> 3, kk = (idx & 7) * 4;
            float4 v = *(const float4*)(A + (size_t)(m0 + mm) * D_ + k0 + kk);
            As[kk][mm] = v.x; As[kk + 1][mm] = v.y; As[kk + 2][mm] = v.z; As[kk + 3][mm] = v.w;
        }
        #pragma unroll
        for (int l = 0; l < 2; l++) {            // B tile: 128x32
            int idx = tid + l * 512;
            int mm = idx >> 3, kk = (idx & 7) * 4;
            float4 v = *(const float4*)(A + (size_t)(n0 + mm) * D_ + k0 + kk);
            Bs[kk][mm] = v.x; Bs[kk + 1][mm] = v.y; Bs[kk + 2][mm] = v.z; Bs[kk + 3][mm] = v.w;
        }
        __syncthreads();
        #pragma unroll
        for (int kk = 0; kk < GBK; kk++) {
            float4 a0 = *(const float4*)&As[kk][ty * 8];
            float4 a1 = *(const float4*)&As[kk][ty * 8 + 4];
            float4 bv = *(const float4*)&Bs[kk][tx * 4];
            float a[8] = { a0.x, a0.y, a0.z, a0.w, a1.x, a1.y, a1.z, a1.w };
            float b[4] = { bv.x, bv.y, bv.z, bv.w };
            #pragma unroll
            for (int i = 0; i < 8; i++)
                #pragma unroll
                for (int j = 0; j < 4; j++) acc[i][j] += a[i] * b[j];
        }
        __syncthreads();
    }
    #pragma unroll
    for (int i = 0; i < 8; i++) {
        float4 st = make_float4(acc[i][0], acc[i][1], acc[i][2], acc[i][3]);
        *(float4*)(Csim + (size_t)(m0 + ty * 8 + i) * N_ + n0 + tx * 4) = st;
    }
}

// ---------------- K3: per-row top-6 by (dist asc, idx asc); drop self; scatter in-edges ----------------
__global__ __launch_bounds__(256) void k_topk(const float* __restrict__ sim,
                                              int* __restrict__ knn,
                                              int* __restrict__ indeg,
                                              int* __restrict__ inlist) {
    const int r = blockIdx.x, tid = threadIdx.x;
    float bd[6]; int bi[6];
    #pragma unroll
    for (int k = 0; k < 6; k++) { bd[k] = INFINITY; bi[k] = 0x7fffffff; }
    const float* srow = sim + (size_t)r * N_;
    for (int j = tid; j < N_; j += 256) {
        float s = srow[j];
        float d = sqrtf(fmaxf(2.f - 2.f * s, 0.f));
        if (d < bd[5] || (d == bd[5] && j < bi[5])) {
            int k = 5;
            while (k > 0 && (d < bd[k - 1] || (d == bd[k - 1] && j < bi[k - 1]))) {
                bd[k] = bd[k - 1]; bi[k] = bi[k - 1]; k--;
            }
            bd[k] = d; bi[k] = j;
        }
    }
    __shared__ float sd[256][6];
    __shared__ int   si[256][6];
    #pragma unroll
    for (int k = 0; k < 6; k++) { sd[tid][k] = bd[k]; si[tid][k] = bi[k]; }
    __syncthreads();
    for (int s = 128; s > 0; s >>= 1) {
        if (tid < s) {
            float md[6]; int mi[6];
            int p = 0, q = 0;
            #pragma unroll
            for (int k = 0; k < 6; k++) {
                float d1 = sd[tid][p], d2 = sd[tid + s][q];
                int i1 = si[tid][p], i2 = si[tid + s][q];
                bool take1 = (d1 < d2) || (d1 == d2 && i1 < i2);
                if (take1) { md[k] = d1; mi[k] = i1; p++; } else { md[k] = d2; mi[k] = i2; q++; }
            }
            #pragma unroll
            for (int k = 0; k < 6; k++) { sd[tid][k] = md[k]; si[tid][k] = mi[k]; }
        }
        __syncthreads();
    }
    if (tid < K_) {
        const int j = si[0][1 + tid];      // drop rank-0 (self)
        knn[(size_t)r * K_ + tid] = j;
        const int pos = atomicAdd(&indeg[j], 1);
        if (pos < CAP_) inlist[(size_t)j * CAP_ + pos] = r;
    }
}

// ---------------- K5: cooperative LAME — sort/unary prologue + iterate (round-9 version) ----------------
__global__ __launch_bounds__(LT_) void k_lame(
    const float* __restrict__ logits, const int* __restrict__ knn,
    const int* __restrict__ indeg, const int* __restrict__ inlist,
    ushort_t* __restrict__ YA, ushort_t* __restrict__ YB,
    float* __restrict__ partials, int* __restrict__ flag,
    float* __restrict__ out)
{
    cg::grid_group grid = cg::this_grid();
    const int tid = threadIdx.x;
    const int wave = tid >> 6, lane = tid & 63;
    const int rbase = blockIdx.x * 16 + wave * 2;   // rows rbase, rbase+1
    const int c0 = lane * 16;
    const bool msk0 = lane <= 62;   // cols c0..c0+7 valid
    const bool msk1 = lane <= 61;   // cols c0+8..c0+15 valid

    // ---- prologue B: stage neighbor lists in LDS, sort in-lists (deterministic) ----
    __shared__ int nb[16][K_ + CAP_ + 3];
    __shared__ int cnts[16];
    #pragma unroll
    for (int rr = 0; rr < 2; rr++) {
        const int w = wave * 2 + rr, r = rbase + rr;
        if (lane == 0) cnts[w] = K_ + min(indeg[r], CAP_);
        if (lane < K_) nb[w][lane] = knn[r * K_ + lane];
        for (int t = lane; t < CAP_; t += 64) nb[w][K_ + t] = inlist[(size_t)r * CAP_ + t];
    }
    __syncthreads();
    if (lane < 2) {   // insertion-sort each row's in-list ascending
        const int w = wave * 2 + lane;
        int* L = &nb[w][K_];
        const int cn = cnts[w] - K_;
        for (int a = 1; a < cn; a++) {
            const int key = L[a];
            int b = a - 1;
            while (b >= 0 && L[b] > key) { L[b + 1] = L[b]; b--; }
            L[b + 1] = key;
        }
    }
    __syncthreads();
    const int cnt2[2] = { cnts[wave * 2], cnts[wave * 2 + 1] };

    // ---- prologue C: u = -log(softmax(logits)+1e-10) in registers ----
    float u[2][16];
    #pragma unroll
    for (int rr = 0; rr < 2; rr++) {
        const float* lp = logits + (size_t)(rbase + rr) * C_;
        float l[16];
        #pragma unroll
        for (int q = 0; q < 4; q++) {
            const int off = c0 + q * 4;
            const int ao = (off + 3 < C_) ? off : 0;   // clamp: input buffer exactly sized
            float4 v = *(const float4*)(lp + ao);
            l[q * 4 + 0] = v.x; l[q * 4 + 1] = v.y; l[q * 4 + 2] = v.z; l[q * 4 + 3] = v.w;
        }
        float mm = -INFINITY;
        #pragma unroll
        for (int k = 0; k < 8; k++) mm = fmaxf(mm, msk0 ? l[k] : -INFINITY);
        #pragma unroll
        for (int k = 8; k < 16; k++) mm = fmaxf(mm, msk1 ? l[k] : -INFINITY);
        #pragma unroll
        for (int o = 32; o > 0; o >>= 1) mm = fmaxf(mm, __shfl_xor(mm, o));
        float e[16];
        float s = 0.f;
        #pragma unroll
        for (int k = 0; k < 8; k++) { e[k] = msk0 ? expf(l[k] - mm) : 0.f; s += e[k]; }
        #pragma unroll
        for (int k = 8; k < 16; k++) { e[k] = msk1 ? expf(l[k] - mm) : 0.f; s += e[k]; }
        #pragma unroll
        for (int o = 32; o > 0; o >>= 1) s += __shfl_xor(s, o);
        const float inv = 1.f / s;
        #pragma unroll
        for (int k = 0; k < 16; k++) u[rr][k] = -logf(e[k] * inv + 1e-10f);
    }

    // gather neighbor-sum of src into acc[16] for row-pair member rr
    auto gather = [&](const ushort_t* __restrict__ src, int rr, float* acc) {
        const int w = wave * 2 + rr, cn = cnt2[rr];
        auto acc16 = [&](uint4 p, uint4 q) {
            acc[0] += bflo(p.x); acc[1] += bfhi(p.x); acc[2] += bflo(p.y); acc[3] += bfhi(p.y);
            acc[4] += bflo(p.z); acc[5] += bfhi(p.z); acc[6] += bflo(p.w); acc[7] += bfhi(p.w);
            acc[8] += bflo(q.x); acc[9] += bfhi(q.x); acc[10] += bflo(q.y); acc[11] += bfhi(q.y);
            acc[12] += bflo(q.z); acc[13] += bfhi(q.z); acc[14] += bflo(q.w); acc[15] += bfhi(q.w);
        };
        int t = 0;
        for (; t + 2 <= cn; t += 2) {
            const int n0 = nb[w][t], n1 = nb[w][t + 1];
            const uint4 p0 = *(const uint4*)(src + (size_t)n0 * C_ + c0);
            const uint4 p1 = *(const uint4*)(src + (size_t)n0 * C_ + c0 + 8);
            const uint4 q0 = *(const uint4*)(src + (size_t)n1 * C_ + c0);
            const uint4 q1 = *(const uint4*)(src + (size_t)n1 * C_ + c0 + 8);
            acc16(p0, p1); acc16(q0, q1);
        }
        if (t < cn) {
            const int n0 = nb[w][t];
            const uint4 p0 = *(const uint4*)(src + (size_t)n0 * C_ + c0);
            const uint4 p1 = *(const uint4*)(src + (size_t)n0 * C_ + c0 + 8);
            acc16(p0, p1);
        }
    };

    // softmax(0.5*acc - u[rr]) -> dst row; returns row energy -(m+logS)
    auto smax = [&](int rr, const float* acc, ushort_t* __restrict__ dst) -> float {
        const int r = rbase + rr;
        float z[16];
        #pragma unroll
        for (int k = 0; k < 16; k++) z[k] = 0.5f * acc[k] - u[rr][k];
        float mm = -INFINITY;
        #pragma unroll
        for (int k = 0; k < 8; k++) mm = fmaxf(mm, msk0 ? z[k] : -INFINITY);
        #pragma unroll
        for (int k = 8; k < 16; k++) mm = fmaxf(mm, msk1 ? z[k] : -INFINITY);
        #pragma unroll
        for (int o = 32; o > 0; o >>= 1) mm = fmaxf(mm, __shfl_xor(mm, o));
        float e[16];
        float s = 0.f;
        #pragma unroll
        for (int k = 0; k < 8; k++) { e[k] = msk0 ? expf(z[k] - mm) : 0.f; s += e[k]; }
        #pragma unroll
        for (int k = 8; k < 16; k++) { e[k] = msk1 ? expf(z[k] - mm) : 0.f; s += e[k]; }
        #pragma unroll
        for (int o = 32; o > 0; o >>= 1) s += __shfl_xor(s, o);
        const float inv = 1.f / s;
        if (msk0) {
            uint4 w;
            w.x = pk(e[0] * inv, e[1] * inv); w.y = pk(e[2] * inv, e[3] * inv);
            w.z = pk(e[4] * inv, e[5] * inv); w.w = pk(e[6] * inv, e[7] * inv);
            *(uint4*)(dst + (size_t)r * C_ + c0) = w;
        }
        if (msk1) {
            uint4 w;
            w.x = pk(e[8] * inv, e[9] * inv); w.y = pk(e[10] * inv, e[11] * inv);
            w.z = pk(e[12] * inv, e[13] * inv); w.w = pk(e[14] * inv, e[15] * inv);
            *(uint4*)(dst + (size_t)r * C_ + c0 + 8) = w;
        }
        return -(mm + logf(s));   // == sum_c Y*(logY - z), exact closed form
    };

    // ---- Y0 = softmax(-unary) -> YA ----
    {
        float zacc[16];
        #pragma unroll
        for (int k = 0; k < 16; k++) zacc[k] = 0.f;
        smax(0, zacc, YA);
        smax(1, zacc, YA);
    }
    if (blockIdx.x == 0 && tid == 0) { flag[0] = 0; flag[1] = 0; }
    grid.sync();

    float oldE = INFINITY;
    const ushort_t* fin = YB;
    for (int it = 0; it < MAXS_; ++it) {
        const ushort_t* src = (it & 1) ? YB : YA;
        ushort_t* dst = (it & 1) ? YA : YB;
        float acc0[16], acc1[16];
        #pragma unroll
        for (int k = 0; k < 16; k++) { acc0[k] = 0.f; acc1[k] = 0.f; }
        gather(src, 0, acc0);
        gather(src, 1, acc1);
        const float E0 = smax(0, acc0, dst);
        const float E1 = smax(1, acc1, dst);
        if (lane == 0) {
            partials[(size_t)(it & 1) * N_ + rbase] = E0;
            partials[(size_t)(it & 1) * N_ + rbase + 1] = E1;
        }
        grid.sync();
        if (blockIdx.x == 0 && wave == 0) {
            const float* P = partials + (size_t)(it & 1) * N_;
            float e = 0.f;
            #pragma unroll
            for (int q = 0; q < 32; q += 4) {
                float4 v = *(const float4*)(P + lane * 32 + q);
                e += ((v.x + v.y) + v.z) + v.w;
            }
            #pragma unroll
            for (int o = 32; o > 0; o >>= 1) e += __shfl_xor(e, o);
            const bool done = (it > 1) && (fabsf(e - oldE) <= 1e-8f * fabsf(oldE));
            oldE = e;
            if (lane == 0) flag[it & 1] = done ? 1 : 0;
        }
        fin = dst;
        if (((volatile const int*)flag)[(it + 1) & 1]) break;  // prev iter's flag: uniform
    }

    #pragma unroll
    for (int rr = 0; rr < 2; rr++) {
        const int r = rbase + rr;
        #pragma unroll
        for (int q = 0; q < 4; q++) {
            if (c0 + q * 4 + 3 < C_) {
                const uint2 w = *(const uint2*)(fin + (size_t)r * C_ + c0 + q * 4);
                float4 o;
                o.x = bflo(w.x); o.y = bfhi(w.x); o.z = bflo(w.y); o.w = bfhi(w.y);
                *(float4*)(out + (size_t)r * C_ + c0 + q * 4) = o;
            }
        }
    }
}

extern "C" void kernel_launch(void* const* d_in, const int* in_sizes, int n_in,
                              void* d_out, int out_size, void* d_ws, size_t ws_size,
                              hipStream_t stream) {
    const float* logits = (const float*)d_in[0];
    const float* feats  = (const float*)d_in[1];
    float* out = (float*)d_out;
    char* ws = (char*)d_ws;

    size_t off = 0;
    auto alloc = [&](size_t b) { size_t o = off; off += (b + 255) & ~(size_t)255; return o; };
    float* fn      = (float*)(ws + alloc((size_t)N_ * D_ * 4));
    float* sim     = (float*)(ws + alloc((size_t)N_ * N_ * 4));   // reused as YA/YB after topk
    int*   knn     = (int*)(ws + alloc((size_t)N_ * K_ * 4));
    int*   indeg   = (int*)(ws + alloc((size_t)N_ * 4));
    int*   inlist  = (int*)(ws + alloc((size_t)N_ * CAP_ * 4));
    float* partials= (float*)(ws + alloc((size_t)2 * N_ * 4));
    int*   flag    = (int*)(ws + alloc(256));
    if (off > ws_size) return;

    ushort_t* YA = (ushort_t*)sim;             // 2 * N*C*2 B = 8.2 MB <= N*N*4 B
    ushort_t* YB = YA + (size_t)N_ * C_;

    k_norm <<<N_, 256, 0, stream>>>(feats, fn);
    (void)hipMemsetAsync(indeg, 0, (size_t)N_ * 4, stream);
    k_gemm <<<dim3(N_ / GTN, N_ / GTM), 512, 0, stream>>>(fn, sim);
    k_topk <<<N_, 256, 0, stream>>>(sim, knn, indeg, inlist);

    const float* p_logits = logits;
    const int* p_knn = knn;
    const int* p_indeg = indeg;
    const int* p_inlist = inlist;
    ushort_t* p_YA = YA;
    ushort_t* p_YB = YB;
    float* p_part = partials;
    int* p_flag = flag;
    float* p_out = out;
    void* args[] = { &p_logits, &p_knn, &p_indeg, &p_inlist, &p_YA, &p_YB, &p_part, &p_flag, &p_out };
    (void)hipLaunchCooperativeKernel((void*)k_lame, dim3(LB_), dim3(LT_), args, 0, stream);
}